// Round 6
// baseline (113.145 us; speedup 1.0000x reference)
//
#include <hip/hip_runtime.h>

// DigitCaps, fp32 in / fp32 out:
//   u [16,1152,8], W [10,1152,16,8], Bp [10,1,1152], out [16,10,16]
// Exact algebra: A[b,d,m] = dot(T[b,d,:], U_hat[b,d,m,:])/sqrt8,
//   T = sum_n U_hat;  C = softmax_d(A);  S = sum_n (Bp+C)*U_hat; squash(S).
// R19: grid repartition. R18 proved sc1 (agent-relaxed) sync is cheap and
// correct, but its n-partitioned grid forced 3 ALL-TO-ALL barriers (576
// blocks) + 2 global reduce phases ~= 25us of sync for 15us of work.
// New grid: 160 blocks = (b,d). T/scores/S are BLOCK-LOCAL (sum over n
// inside the block); the only cross-block need is softmax over d ->
// ONE barrier over the 10 sibling blocks of the same b. Votes uh[72]
// live in registers across it. A (737KB) via sc1 through IF$.
constexpr int BN = 16, NN = 1152, DP = 8, ND = 10, DD = 16;
constexpr int NBLK = BN * ND;        // 160 blocks, blk = b*ND + d
constexpr int KPT = NN / 16;         // 72 n's per thread (g-strided)
constexpr unsigned MAG1 = 0xC0FFEE01u;
constexpr int SPIN_CAP = 1 << 20;    // failsafe: wrong-answer, not hang

__device__ __forceinline__ float ld_dev(const float* p) {
    return __hip_atomic_load(p, __ATOMIC_RELAXED, __HIP_MEMORY_SCOPE_AGENT);
}
__device__ __forceinline__ void st_dev(float* p, float v) {
    __hip_atomic_store(p, v, __ATOMIC_RELAXED, __HIP_MEMORY_SCOPE_AGENT);
}

// ===== one kernel, one 10-block barrier =====
__global__ __launch_bounds__(256) void caps_one(
    const float* __restrict__ u, const float* __restrict__ W,
    const float* __restrict__ Bp, float* __restrict__ A,   // [BN][ND][NN]
    unsigned* __restrict__ flags, float* __restrict__ out)
{
    __shared__ float ul[NN * DP];        // 36,864 B: u[b] staged
    __shared__ float coeff[NN];          //  4,608 B
    __shared__ float Tpart[16][17];      //  1,088 B (padded)
    __shared__ float Tl[16];
    __shared__ float Spart[16][17];      //  1,088 B

    const int t = threadIdx.x;
    const int blk = blockIdx.x;
    const int b = blk / ND, d = blk - b * ND;
    const int j = t & 15, g = t >> 4;    // j-lanes contiguous within wave
    constexpr float RS8 = 0.35355339059327373f;    // 1/sqrt(8)

    // ---- stage u[b]: 2304 float4, 9/thread, coalesced ----
    {
        const float4* src = reinterpret_cast<const float4*>(u + (size_t)b * NN * DP);
        float4* dst4 = reinterpret_cast<float4*>(ul);
        for (int i = t; i < NN * DP / 4; i += 256) dst4[i] = src[i];
    }
    __syncthreads();

    // ---- phase 1a: votes uh[k] = dot(W[d,n,j,:], u[b,n,:]), n = g+16k ----
    // W addresses: 16 j-lanes x 32B contiguous, 4 g-groups/wave adjacent
    // -> 2KB contiguous per wave per k. Perfectly coalesced.
    float uh[KPT];
    float tacc = 0.f;
    const float* Wd = W + (size_t)d * NN * DD * DP;
#pragma unroll 8
    for (int k = 0; k < KPT; ++k) {
        const int n = g + 16 * k;
        const float4 w0 = *reinterpret_cast<const float4*>(
            Wd + ((size_t)n * DD + j) * DP);
        const float4 w1 = *reinterpret_cast<const float4*>(
            Wd + ((size_t)n * DD + j) * DP + 4);
        const float4 u0 = reinterpret_cast<const float4*>(ul)[n * 2];
        const float4 u1 = reinterpret_cast<const float4*>(ul)[n * 2 + 1];
        const float s = w0.x * u0.x + w0.y * u0.y + w0.z * u0.z + w0.w * u0.w
                      + w1.x * u1.x + w1.y * u1.y + w1.z * u1.z + w1.w * u1.w;
        uh[k] = s;
        tacc += s;
    }

    // ---- phase 1b: T[j] = sum over all n (k-order, then g-order) ----
    Tpart[g][j] = tacc;
    __syncthreads();
    if (t < 16) {
        float s = 0.f;
#pragma unroll
        for (int gg = 0; gg < 16; ++gg) s += Tpart[gg][t];
        Tl[t] = s;
    }
    __syncthreads();

    // ---- phase 1c: A[n] = RS8 * sum_j T[j]*uh[n,j] -> global (sc1) ----
    {
        float* Arow = A + (size_t)blk * NN;
        const float Tj = Tl[j];
        for (int k = 0; k < KPT; ++k) {
            float v = Tj * uh[k];                  // butterfly over 16 j-lanes
            v += __shfl_xor(v, 8, 16);
            v += __shfl_xor(v, 4, 16);
            v += __shfl_xor(v, 2, 16);
            v += __shfl_xor(v, 1, 16);
            if (j == 0) st_dev(Arow + (g + 16 * k), v * RS8);
        }
    }

    // ---- barrier over the 10 blocks of this b-group (R18 semantics:
    // syncthreads drains each thread's sc1 stores to IF$; relaxed flag) ----
    __syncthreads();
    if (t == 0)
        __hip_atomic_store(&flags[blk], MAG1, __ATOMIC_RELAXED,
                           __HIP_MEMORY_SCOPE_AGENT);
    if (t < ND) {
        int spins = 0;
        while (__hip_atomic_load(&flags[b * ND + t], __ATOMIC_RELAXED,
                                 __HIP_MEMORY_SCOPE_AGENT) != MAG1) {
            __builtin_amdgcn_s_sleep(2);           // ~128 cyc between polls
            if (++spins > SPIN_CAP) break;
        }
    }
    asm volatile("" ::: "memory");
    __syncthreads();

    // ---- phase 2a: coeff[n] = Bp[d,n] + softmax_q(A[b,:,n])[d] ----
    {
        const float* Ab = A + (size_t)b * ND * NN;
        for (int n = t; n < NN; n += 256) {
            float aq[ND];
#pragma unroll
            for (int q = 0; q < ND; ++q) aq[q] = ld_dev(Ab + (size_t)q * NN + n);
            float m = aq[0];
#pragma unroll
            for (int q = 1; q < ND; ++q) m = fmaxf(m, aq[q]);
            float se = 0.f;
#pragma unroll
            for (int q = 0; q < ND; ++q) { aq[q] = expf(aq[q] - m); se += aq[q]; }
            coeff[n] = Bp[(size_t)d * NN + n] + aq[d] / se;
        }
    }
    __syncthreads();

    // ---- phase 2b: S[j] = sum_n coeff[n]*uh[n,j]; squash; out ----
    float sacc = 0.f;
#pragma unroll 8
    for (int k = 0; k < KPT; ++k) sacc += coeff[g + 16 * k] * uh[k];
    Spart[g][j] = sacc;
    __syncthreads();
    if (t < 16) {                        // t = j
        float Sv = 0.f;
#pragma unroll
        for (int gg = 0; gg < 16; ++gg) Sv += Spart[gg][t];
        float n2 = Sv * Sv;
#pragma unroll
        for (int off = 8; off >= 1; off >>= 1) n2 += __shfl_xor(n2, off, 16);
        const float nrm = sqrtf(n2);
        const float coef = 1.f - 1.f / (expf(nrm) + 1e-7f);
        out[((size_t)b * ND + d) * DD + t] = Sv * (coef / (nrm + 1e-7f));
    }
}

extern "C" void kernel_launch(void* const* d_in, const int* in_sizes, int n_in,
                              void* d_out, int out_size, void* d_ws, size_t ws_size,
                              hipStream_t stream) {
    const float* u  = nullptr;   // 147456
    const float* W  = nullptr;   // 1474560
    const float* Bp = nullptr;   // 11520
    for (int i = 0; i < n_in; ++i) {
        const int s = in_sizes[i];
        if (s == BN * NN * DP)            u  = (const float*)d_in[i];
        else if (s == ND * NN * DD * DP)  W  = (const float*)d_in[i];
        else if (s == ND * NN)            Bp = (const float*)d_in[i];
    }
    float* out = (float*)d_out;
    char*  wsc = (char*)d_ws;
    // layout: A [160][1152] fp32 = 737,280 B | flags[160] at 1 MB.
    // ws poisoned per iteration -> flags start != MAG1 every call. During
    // rocprof replay without re-poison, stale MAG1 only releases early
    // against stale-but-identical A (deterministic inputs) -> benign.
    float*    A     = (float*)wsc;
    unsigned* flags = (unsigned*)(wsc + (1u << 20));

    caps_one<<<dim3(NBLK), 256, 0, stream>>>(u, W, Bp, A, flags, out);
}

// Round 7
// 76.431 us; speedup vs baseline: 1.4804x; 1.4804x over previous
//
#include <hip/hip_runtime.h>

// DigitCaps, fp32 in / fp32 out:
//   u [16,1152,8], W [10,1152,16,8], Bp [10,1,1152], out [16,10,16]
// Exact algebra: A[b,d,m] = dot(T[b,d,:], U_hat[b,d,m,:])/sqrt8,
//   T = sum_n U_hat;  C = softmax_d(A);  S = sum_n (Bp+C)*U_hat; squash(S).
// R20: R19's (b,d)-partitioned single kernel (1 ten-block barrier, proven
// correct) with fixed GEOMETRY. R19 counters: 62us, occupancy 2.5-5.9%
// (1 wave/SIMD, 96 CUs idle), VGPR 84 (uh[72]), FETCH 22.7MB (=3.8x W:
// same-d blocks on different XCDs re-fetch W from HBM). Fixes:
//  (1) 1024-thread blocks: 4 waves/SIMD, uh[18], 36 indep W-loads/thread.
//  (2) XCD-chunked d-major mapping: each XCD sees 20 consecutive d-major
//      blocks = 2 distinct d's -> W[d] fetched once per XCD L2, re-hit by
//      ~10-20 blocks (HBM-latency stalls -> L2-latency stalls).
constexpr int BN = 16, NN = 1152, DP = 8, ND = 10, DD = 16;
constexpr int NBLK = BN * ND;        // 160 blocks
constexpr int GG = 64;               // g-groups per block (1024 threads)
constexpr int KPT = NN / GG;         // 18 n's per thread
constexpr unsigned MAG1 = 0xC0FFEE01u;
constexpr int SPIN_CAP = 1 << 20;    // failsafe: wrong-answer, not hang

__device__ __forceinline__ float ld_dev(const float* p) {
    return __hip_atomic_load(p, __ATOMIC_RELAXED, __HIP_MEMORY_SCOPE_AGENT);
}
__device__ __forceinline__ void st_dev(float* p, float v) {
    __hip_atomic_store(p, v, __ATOMIC_RELAXED, __HIP_MEMORY_SCOPE_AGENT);
}

// ===== one kernel, one 10-block barrier =====
__global__ __launch_bounds__(1024) void caps_one(
    const float* __restrict__ u, const float* __restrict__ W,
    const float* __restrict__ Bp, float* __restrict__ A,   // [BN][ND][NN]
    unsigned* __restrict__ flags, float* __restrict__ out)
{
    __shared__ float ul[NN * DP];        // 36,864 B: u[b] staged
    __shared__ float coeff[NN];          //  4,608 B
    __shared__ float Tpart[GG][17];      //  4,352 B (padded)
    __shared__ float Tl[16];
    __shared__ float Spart[GG][17];      //  4,352 B

    const int t = threadIdx.x;
    const int x = blockIdx.x;
    // XCD-chunked d-major: XCD (x&7) owns 20 consecutive d-major indices
    // -> only 2 distinct d's per XCD -> W[d] lives in that XCD's L2.
    const int i = (x & 7) * 20 + (x >> 3);
    const int b = i & 15, d = i >> 4;
    const int j = t & 15, g = t >> 4;    // g in 0..63
    constexpr float RS8 = 0.35355339059327373f;    // 1/sqrt(8)

    // ---- stage u[b]: 2304 float4, coalesced ----
    {
        const float4* src = reinterpret_cast<const float4*>(u + (size_t)b * NN * DP);
        float4* dst4 = reinterpret_cast<float4*>(ul);
        for (int i2 = t; i2 < NN * DP / 4; i2 += 1024) dst4[i2] = src[i2];
    }
    __syncthreads();

    // ---- phase 1a: votes uh[k] = dot(W[d,n,j,:], u[b,n,:]), n = g+64k ----
    // Per wave: 4 consecutive g x 16 j -> 2KB contiguous W per k. LDS u
    // reads: 16 j-lanes broadcast same addr; 4 g's hit distinct banks.
    float uh[KPT];
    float tacc = 0.f;
    const float* Wd = W + (size_t)d * NN * DD * DP;
#pragma unroll 6
    for (int k = 0; k < KPT; ++k) {
        const int n = g + GG * k;
        const float4 w0 = *reinterpret_cast<const float4*>(
            Wd + ((size_t)n * DD + j) * DP);
        const float4 w1 = *reinterpret_cast<const float4*>(
            Wd + ((size_t)n * DD + j) * DP + 4);
        const float4 u0 = reinterpret_cast<const float4*>(ul)[n * 2];
        const float4 u1 = reinterpret_cast<const float4*>(ul)[n * 2 + 1];
        const float s = w0.x * u0.x + w0.y * u0.y + w0.z * u0.z + w0.w * u0.w
                      + w1.x * u1.x + w1.y * u1.y + w1.z * u1.z + w1.w * u1.w;
        uh[k] = s;
        tacc += s;
    }

    // ---- phase 1b: T[j] = sum over all n (k-order, then g-order) ----
    Tpart[g][j] = tacc;
    __syncthreads();
    if (t < 16) {
        float s = 0.f;
#pragma unroll
        for (int gg = 0; gg < GG; ++gg) s += Tpart[gg][t];
        Tl[t] = s;
    }
    __syncthreads();

    // ---- phase 1c: A[n] = RS8 * sum_j T[j]*uh[n,j] -> global (sc1) ----
    {
        float* Arow = A + (size_t)(b * ND + d) * NN;
        const float Tj = Tl[j];
#pragma unroll
        for (int k = 0; k < KPT; ++k) {
            float v = Tj * uh[k];                  // butterfly over 16 j-lanes
            v += __shfl_xor(v, 8, 16);
            v += __shfl_xor(v, 4, 16);
            v += __shfl_xor(v, 2, 16);
            v += __shfl_xor(v, 1, 16);
            if (j == 0) st_dev(Arow + (g + GG * k), v * RS8);
        }
    }

    // ---- barrier over the 10 blocks of this b-group (R18 semantics:
    // syncthreads drains each thread's sc1 stores to IF$; relaxed flag) ----
    __syncthreads();
    if (t == 0)
        __hip_atomic_store(&flags[b * ND + d], MAG1, __ATOMIC_RELAXED,
                           __HIP_MEMORY_SCOPE_AGENT);
    if (t < ND) {
        int spins = 0;
        while (__hip_atomic_load(&flags[b * ND + t], __ATOMIC_RELAXED,
                                 __HIP_MEMORY_SCOPE_AGENT) != MAG1) {
            __builtin_amdgcn_s_sleep(2);           // ~128 cyc between polls
            if (++spins > SPIN_CAP) break;
        }
    }
    asm volatile("" ::: "memory");
    __syncthreads();

    // ---- phase 2a: coeff[n] = Bp[d,n] + softmax_q(A[b,:,n])[d] ----
    {
        const float* Ab = A + (size_t)b * ND * NN;
        for (int n = t; n < NN; n += 1024) {
            float aq[ND];
#pragma unroll
            for (int q = 0; q < ND; ++q) aq[q] = ld_dev(Ab + (size_t)q * NN + n);
            float m = aq[0];
#pragma unroll
            for (int q = 1; q < ND; ++q) m = fmaxf(m, aq[q]);
            float se = 0.f;
#pragma unroll
            for (int q = 0; q < ND; ++q) { aq[q] = expf(aq[q] - m); se += aq[q]; }
            coeff[n] = Bp[(size_t)d * NN + n] + aq[d] / se;
        }
    }
    __syncthreads();

    // ---- phase 2b: S[j] = sum_n coeff[n]*uh[n,j]; squash; out ----
    float sacc = 0.f;
#pragma unroll
    for (int k = 0; k < KPT; ++k) sacc += coeff[g + GG * k] * uh[k];
    Spart[g][j] = sacc;
    __syncthreads();
    if (t < 16) {                        // t = j
        float Sv = 0.f;
#pragma unroll
        for (int gg = 0; gg < GG; ++gg) Sv += Spart[gg][t];
        float n2 = Sv * Sv;
#pragma unroll
        for (int off = 8; off >= 1; off >>= 1) n2 += __shfl_xor(n2, off, 16);
        const float nrm = sqrtf(n2);
        const float coef = 1.f - 1.f / (expf(nrm) + 1e-7f);
        out[((size_t)b * ND + d) * DD + t] = Sv * (coef / (nrm + 1e-7f));
    }
}

extern "C" void kernel_launch(void* const* d_in, const int* in_sizes, int n_in,
                              void* d_out, int out_size, void* d_ws, size_t ws_size,
                              hipStream_t stream) {
    const float* u  = nullptr;   // 147456
    const float* W  = nullptr;   // 1474560
    const float* Bp = nullptr;   // 11520
    for (int i = 0; i < n_in; ++i) {
        const int s = in_sizes[i];
        if (s == BN * NN * DP)            u  = (const float*)d_in[i];
        else if (s == ND * NN * DD * DP)  W  = (const float*)d_in[i];
        else if (s == ND * NN)            Bp = (const float*)d_in[i];
    }
    float* out = (float*)d_out;
    char*  wsc = (char*)d_ws;
    // layout: A [16][10][1152] fp32 = 737,280 B | flags[160] at 1 MB.
    // ws poisoned per iteration -> flags start != MAG1 every call. During
    // rocprof replay without re-poison, stale MAG1 only releases early
    // against stale-but-identical A (deterministic inputs) -> benign.
    float*    A     = (float*)wsc;
    unsigned* flags = (unsigned*)(wsc + (1u << 20));

    caps_one<<<dim3(NBLK), 1024, 0, stream>>>(u, W, Bp, A, flags, out);
}